// Round 9
// baseline (2337.230 us; speedup 1.0000x reference)
//
#include <hip/hip_runtime.h>

#define NJ 32
#define NE 1024
#define CD 128
#define HID 256
#define ROWS 8192

struct Lv { int nj; int j[5]; int p[5]; };

// ---------------------------------------------------------------------------
// codebook norms: nrm[j*NE+n] = sum_c emb[j][n][c]^2   (4 lanes per code row)
// ---------------------------------------------------------------------------
__global__ __launch_bounds__(256) void norms_kernel(const float* __restrict__ emb,
                                                    float* __restrict__ nrm) {
  int gid = blockIdx.x * 256 + threadIdx.x;
  int n = gid >> 2, l = gid & 3;           // n in [0, NJ*NE)
  const float* row = emb + (size_t)n * CD;
  float s = 0.f;
#pragma unroll
  for (int i = 0; i < 8; ++i) {
    float4 v = *(const float4*)&row[(l + 4 * i) * 4];
    s += v.x * v.x + v.y * v.y + v.z * v.z + v.w * v.w;
  }
  s += __shfl_xor(s, 1);
  s += __shfl_xor(s, 2);
  if (l == 0) nrm[n] = s;
}

// ---------------------------------------------------------------------------
// fused per-level kernel. One [128][HSP] LDS buffer aliased across phases
// (xs -> as_ -> hs) + small es staging buffer; weights read from global
// (L1/L2); e-chunk staging is REGISTER-PREFETCHED one round ahead so L2
// latency hides under compute. 3 blocks/CU at RB=64.
// Phase 1: rg=tid>>5 rows, cg=tid&31 cols {qcA,qcB}. Phase 3: rr=tid>>4,
// cc=tid&15 cols {cc*4, 64+cc*4}. Phase 4: wave w4 owns R4 rows; lane l4
// owns codes {l4*4..+3} of each 256-code chunk (4 chunks).
// ---------------------------------------------------------------------------
template <int RB>
__global__ __launch_bounds__(256) void fused_level(
    const float* __restrict__ z, const float* __restrict__ emb,
    const float* __restrict__ W1, const float* __restrict__ b1,
    const float* __restrict__ lng, const float* __restrict__ lnb,
    const float* __restrict__ W2, const float* __restrict__ b2,
    const float* __restrict__ nrm,
    float* __restrict__ zq, float* __restrict__ idx_out,
    float* __restrict__ partials, Lv lv, int pbase) {
  constexpr int RPG = RB / 8;          // rows/thread, phase 1
  constexpr int R3  = RB / 16;         // rows/thread, phase 3
  constexpr int R4  = RB / 4;          // rows/thread, phase 4
  constexpr int HSP = RB + 4;
  constexpr int BPJ = ROWS / RB;
  constexpr int SMEM = 128 * HSP + 16 * 260;

  __shared__ __align__(16) float smem[SMEM];
  __shared__ float wsum[4];
  float* xs  = smem;                   // phase 1: [128 k][HSP]
  float* as_ = smem;                   // phase 3 input halves
  float* hs  = smem;                   // phase 3 out / phase 4
  float* es  = smem + 128 * HSP;       // phase 4: [16][260]

  const int tid = threadIdx.x;
  const int rg = tid >> 5, cg = tid & 31;
  const int u = cg & 15;
  const int qcA = (cg >> 4) * 128 + u * 4;
  const int qcB = qcA + 64;
  const int jl = blockIdx.x / BPJ;
  const int row0 = (blockIdx.x % BPJ) * RB;
  const int jj = lv.j[jl], pj = lv.p[jl];
  const size_t rstride = (size_t)NJ * CD;

  if (pj >= 0) {
    // ====== phase 1: a1 = [e_parent | z_j] @ W1 (W1 global; xs in LDS) ====
    float acc1[RPG][8];
#pragma unroll
    for (int r = 0; r < RPG; ++r)
#pragma unroll
      for (int c = 0; c < 8; ++c) acc1[r][c] = 0.f;

#pragma unroll 1
    for (int ch = 0; ch < 2; ++ch) {
      if (ch) __syncthreads();   // xs consumers of chunk 0 done
      // stage x chunk [128 dims][RB rows]: 8-lane x 128B global segments
#pragma unroll
      for (int v = 0; v < RB / 8; ++v) {
        int idx = v * 256 + tid;
        int kq = idx & 7;                          // dims kq*4 within group
        int r = (idx >> 3) & (RB - 1);             // row
        int g32 = idx >> (3 + (RB == 64 ? 6 : (RB == 32 ? 5 : 4)));  // dim group
        const float* src = (ch == 0)
            ? (zq + (size_t)(row0 + r) * rstride + (size_t)pj * CD + g32 * 32 + kq * 4)
            : (z  + (size_t)(row0 + r) * rstride + (size_t)jj * CD + g32 * 32 + kq * 4);
        float4 x4 = *(const float4*)src;
        int kb = g32 * 32 + kq * 4;
        xs[(kb + 0) * HSP + r] = x4.x;
        xs[(kb + 1) * HSP + r] = x4.y;
        xs[(kb + 2) * HSP + r] = x4.z;
        xs[(kb + 3) * HSP + r] = x4.w;
      }
      __syncthreads();
#pragma unroll 4
      for (int kk = 0; kk < 128; ++kk) {
        float xr[RPG], wc[8];
        const float* Wrow = &W1[(size_t)(ch * 128 + kk) * HID];
        *(float4*)&wc[0] = *(const float4*)&Wrow[qcA];
        *(float4*)&wc[4] = *(const float4*)&Wrow[qcB];
        if constexpr (RPG >= 4) {
#pragma unroll
          for (int g = 0; g < RPG / 4; ++g)
            *(float4*)&xr[g * 4] = *(const float4*)&xs[kk * HSP + rg * RPG + g * 4];
        } else {
#pragma unroll
          for (int g = 0; g < RPG; ++g) xr[g] = xs[kk * HSP + rg * RPG + g];
        }
#pragma unroll
        for (int r = 0; r < RPG; ++r)
#pragma unroll
          for (int c = 0; c < 8; ++c)
            acc1[r][c] += xr[r] * wc[c];
      }
    }

    // ====== phase 2: +b1, LayerNorm, ReLU — round-1 bit-exact tree =========
    {
      float bb[8], gg[8], be[8];
      *(float4*)&bb[0] = *(const float4*)&b1[qcA];
      *(float4*)&bb[4] = *(const float4*)&b1[qcB];
      *(float4*)&gg[0] = *(const float4*)&lng[qcA];
      *(float4*)&gg[4] = *(const float4*)&lng[qcB];
      *(float4*)&be[0] = *(const float4*)&lnb[qcA];
      *(float4*)&be[4] = *(const float4*)&lnb[qcB];
#pragma unroll
      for (int r = 0; r < RPG; ++r) {
        float s0 = 0.f, q0 = 0.f;
#pragma unroll
        for (int j = 0; j < 8; ++j) {
          float v = acc1[r][j] + bb[j];
          acc1[r][j] = v;
          s0 += v; q0 += v * v;
        }
        float si = __shfl_xor(s0, 16), qi = __shfl_xor(q0, 16);
        float s1 = si, q1 = qi;
#pragma unroll
        for (int j = 0; j < 8; ++j) {
          float v = acc1[r][j];
          s1 += v; q1 += v * v;
        }
#pragma unroll
        for (int m = 1; m < 16; m <<= 1) {
          s1 += __shfl_xor(s1, m); q1 += __shfl_xor(q1, m);
        }
        float s2 = __shfl_xor(s1, 16), q2 = __shfl_xor(q1, 16);
        float Sx = (cg & 16) ? s1 : s2;
        float Qx = (cg & 16) ? q1 : q2;
        float mu = Sx * (1.f / HID);
        float va = Qx * (1.f / HID) - mu * mu;
        float iv = 1.f / sqrtf(va + 1e-5f);
#pragma unroll
        for (int j = 0; j < 8; ++j) {
          float a = (acc1[r][j] - mu) * iv * gg[j] + be[j];
          acc1[r][j] = fmaxf(a, 0.f);
        }
      }
    }

    // ====== phase 3: h = a @ W2 + b2 (W2 global; as_ halves in LDS) =======
    const int cc = tid & 15, rr = tid >> 4;
    const int qA = cc * 4, qB = qA + 64;
    float acc2[R3][8];
#pragma unroll
    for (int r = 0; r < R3; ++r)
#pragma unroll
      for (int c = 0; c < 8; ++c) acc2[r][c] = 0.f;

#pragma unroll 1
    for (int half = 0; half < 2; ++half) {
      __syncthreads();   // xs (half 0) / as_ half-0 readers done
      if ((cg >> 4) == half) {
#pragma unroll
        for (int j = 0; j < 8; ++j) {
          int kl = (j >> 2) * 64 + u * 4 + (j & 3);
#pragma unroll
          for (int g = 0; g < RPG; ++g)
            as_[kl * HSP + rg * RPG + g] = acc1[g][j];
        }
      }
      __syncthreads();
#pragma unroll 4
      for (int kk = 0; kk < 128; ++kk) {
        float ar[R3], w2[8];
        const float* Wrow = &W2[(size_t)(half * 128 + kk) * CD];
        *(float4*)&w2[0] = *(const float4*)&Wrow[qA];
        *(float4*)&w2[4] = *(const float4*)&Wrow[qB];
        if constexpr (R3 >= 4) {
#pragma unroll
          for (int g = 0; g < R3 / 4; ++g)
            *(float4*)&ar[g * 4] = *(const float4*)&as_[kk * HSP + rr * R3 + g * 4];
        } else {
#pragma unroll
          for (int g = 0; g < R3; ++g) ar[g] = as_[kk * HSP + rr * R3 + g];
        }
#pragma unroll
        for (int r = 0; r < R3; ++r)
#pragma unroll
          for (int c = 0; c < 8; ++c)
            acc2[r][c] += ar[r] * w2[c];
      }
    }
    __syncthreads();   // all as_ reads done; buffer becomes hs
    {
      float bbA[4], bbB[4];
      *(float4*)&bbA[0] = *(const float4*)&b2[qA];
      *(float4*)&bbB[0] = *(const float4*)&b2[qB];
#pragma unroll
      for (int c = 0; c < 8; ++c) {
        int col = (c < 4) ? (qA + c) : (qB + c - 4);
        float bb2 = (c < 4) ? bbA[c] : bbB[c - 4];
#pragma unroll
        for (int r = 0; r < R3; ++r)
          hs[col * HSP + rr * R3 + r] = acc2[r][c] + bb2;
      }
    }
  } else {
    // root joint: h = z_j directly
#pragma unroll
    for (int v = 0; v < RB / 8; ++v) {
      int idx = v * 256 + tid;
      int r = idx >> 5, c4 = idx & 31;
      float4 vz = *(const float4*)&z[(size_t)(row0 + r) * rstride + (size_t)jj * CD + c4 * 4];
      hs[(c4 * 4 + 0) * HSP + r] = vz.x;
      hs[(c4 * 4 + 1) * HSP + r] = vz.y;
      hs[(c4 * 4 + 2) * HSP + r] = vz.z;
      hs[(c4 * 4 + 3) * HSP + r] = vz.w;
    }
  }

  // ====== phase 4: d = ||E||^2 - 2 h.E ; 4 chunks x 256 codes;
  //        R4 rows x 4 codes per thread; reg-prefetched staging ============
  const int w4 = tid >> 6;     // wave owns rows w4*R4 .. +R4-1
  const int l4 = tid & 63;     // lane owns codes {l4*4..+3} per chunk
  const int n0 = tid >> 2, kqe = tid & 3;   // staging assignment
  float mnv[R4]; int mni[R4];
#pragma unroll
  for (int r = 0; r < R4; ++r) { mnv[r] = 3.402823e38f; mni[r] = 0; }
  const float* embJ = emb + (size_t)jj * NE * CD;
  const float* nrmJ = nrm + jj * NE;

  float4 pf0, pf1, pf2, pf3;
#define LOADP(pp, kcc) { \
    const float* bp = embJ + ((size_t)((pp) * 256 + n0)) * CD + (kcc) * 16 + kqe * 4; \
    pf0 = *(const float4*)(bp); \
    pf1 = *(const float4*)(bp + (size_t)64 * CD); \
    pf2 = *(const float4*)(bp + (size_t)128 * CD); \
    pf3 = *(const float4*)(bp + (size_t)192 * CD); }

  LOADP(0, 0);
#pragma unroll 1
  for (int p = 0; p < 4; ++p) {
    float4 nr = *(const float4*)&nrmJ[p * 256 + l4 * 4];  // early issue
    float acc4[R4][4];
#pragma unroll
    for (int r = 0; r < R4; ++r)
#pragma unroll
      for (int c = 0; c < 4; ++c) acc4[r][c] = 0.f;

#pragma unroll 1
    for (int kc = 0; kc < 8; ++kc) {
      __syncthreads();   // es free (prev round consumers done) / hs ready
      // commit prefetched chunk [16 dims][256 codes]
      {
        float* e0 = &es[(kqe * 4 + 0) * 260];
        float* e1 = &es[(kqe * 4 + 1) * 260];
        float* e2 = &es[(kqe * 4 + 2) * 260];
        float* e3 = &es[(kqe * 4 + 3) * 260];
        e0[n0]       = pf0.x; e1[n0]       = pf0.y; e2[n0]       = pf0.z; e3[n0]       = pf0.w;
        e0[n0 + 64]  = pf1.x; e1[n0 + 64]  = pf1.y; e2[n0 + 64]  = pf1.z; e3[n0 + 64]  = pf1.w;
        e0[n0 + 128] = pf2.x; e1[n0 + 128] = pf2.y; e2[n0 + 128] = pf2.z; e3[n0 + 128] = pf2.w;
        e0[n0 + 192] = pf3.x; e1[n0 + 192] = pf3.y; e2[n0 + 192] = pf3.z; e3[n0 + 192] = pf3.w;
      }
      // issue next round's loads (hidden under this round's compute)
      if (!(p == 3 && kc == 7)) {
        int np = (kc == 7) ? p + 1 : p;
        int nk = (kc == 7) ? 0 : kc + 1;
        LOADP(np, nk);
      }
      __syncthreads();   // es ready
#pragma unroll 4
      for (int kk = 0; kk < 16; ++kk) {
        int c = kc * 16 + kk;
        float hr[R4], ec[4];
#pragma unroll
        for (int g = 0; g < R4 / 4; ++g)
          *(float4*)&hr[g * 4] = *(const float4*)&hs[c * HSP + w4 * R4 + g * 4];
        *(float4*)&ec[0] = *(const float4*)&es[kk * 260 + l4 * 4];
#pragma unroll
        for (int r = 0; r < R4; ++r)
#pragma unroll
          for (int c2 = 0; c2 < 4; ++c2)
            acc4[r][c2] += hr[r] * ec[c2];
      }
    }
    // min update, ascending-n order with strict < (first-occurrence ties)
    {
      float nrr[4] = {nr.x, nr.y, nr.z, nr.w};
#pragma unroll
      for (int r = 0; r < R4; ++r) {
#pragma unroll
        for (int j = 0; j < 4; ++j) {
          float d = nrr[j] - 2.f * acc4[r][j];
          int n = p * 256 + l4 * 4 + j;
          if (d < mnv[r]) { mnv[r] = d; mni[r] = n; }
        }
      }
    }
  }
#undef LOADP

  // cross-lane argmin reduce over 64 lanes, tie -> smaller index
#pragma unroll
  for (int r = 0; r < R4; ++r) {
    float mv = mnv[r]; int mi = mni[r];
#pragma unroll
    for (int m = 1; m < 64; m <<= 1) {
      float om = __shfl_xor(mv, m); int oi = __shfl_xor(mi, m);
      if (om < mv || (om == mv && oi < mi)) { mv = om; mi = oi; }
    }
    mnv[r] = mv; mni[r] = mi;
  }

  // gather e, write z_q + indices, accumulate loss (lane covers 2 cols)
  float lsum = 0.f;
#pragma unroll
  for (int r = 0; r < R4; ++r) {
    int row = w4 * R4 + r;
    int id = mni[r];
    const float* erow = embJ + (size_t)id * CD;
    float2 ev = *(const float2*)&erow[l4 * 2];
    float h0 = hs[(l4 * 2 + 0) * HSP + row];
    float h1 = hs[(l4 * 2 + 1) * HSP + row];
    float dx = ev.x - h0, dy = ev.y - h1;
    lsum += dx * dx + dy * dy;
    *(float2*)&zq[(size_t)(row0 + row) * rstride + (size_t)jj * CD + l4 * 2] = ev;
    if (l4 == r) idx_out[(size_t)(row0 + row) * NJ + jj] = (float)id;
  }
#pragma unroll
  for (int m = 1; m < 64; m <<= 1) lsum += __shfl_xor(lsum, m);
  if (l4 == 0) wsum[w4] = lsum;
  __syncthreads();
  if (tid == 0) partials[pbase + blockIdx.x] = wsum[0] + wsum[1] + wsum[2] + wsum[3];
}

// ---------------------------------------------------------------------------
// deterministic loss reduction
// ---------------------------------------------------------------------------
__global__ __launch_bounds__(256) void loss_reduce(const float* __restrict__ p, int n,
                                                   float* __restrict__ out) {
  __shared__ float ws[4];
  float s = 0.f;
  for (int i = threadIdx.x; i < n; i += 256) s += p[i];
#pragma unroll
  for (int m = 1; m < 64; m <<= 1) s += __shfl_xor(s, m);
  if ((threadIdx.x & 63) == 0) ws[threadIdx.x >> 6] = s;
  __syncthreads();
  if (threadIdx.x == 0)
    out[0] = (ws[0] + ws[1] + ws[2] + ws[3]) * (1.25f / (1048576.f * 32.f));
}

extern "C" void kernel_launch(void* const* d_in, const int* in_sizes, int n_in,
                              void* d_out, int out_size, void* d_ws, size_t ws_size,
                              hipStream_t stream) {
  const float* z = (const float*)d_in[0];
  const float* emb = (const float*)d_in[1];
  const float* W1 = (const float*)d_in[2];
  const float* b1 = (const float*)d_in[3];
  const float* lng = (const float*)d_in[4];
  const float* lnb = (const float*)d_in[5];
  const float* W2 = (const float*)d_in[6];
  const float* b2 = (const float*)d_in[7];

  float* zq = (float*)d_out;
  float* loss = zq + (size_t)ROWS * NJ * CD;  // 33,554,432
  float* idxo = loss + 1;

  float* nrm = (float*)d_ws;           // NJ*NE floats
  float* partials = nrm + NJ * NE;     // <= 5760 floats

  norms_kernel<<<NJ * NE * 4 / 256, 256, 0, stream>>>(emb, nrm);

  static const Lv levels[11] = {
      {1, {0, 0, 0, 0, 0}, {-1, 0, 0, 0, 0}},
      {3, {1, 6, 11, 0, 0}, {0, 0, 0, 0, 0}},
      {3, {2, 7, 12, 0, 0}, {1, 6, 11, 0, 0}},
      {5, {3, 8, 13, 16, 24}, {2, 7, 12, 12, 12}},
      {5, {4, 9, 14, 17, 25}, {3, 8, 13, 16, 24}},
      {5, {5, 10, 15, 18, 26}, {4, 9, 14, 17, 25}},
      {2, {19, 27, 0, 0, 0}, {18, 26, 0, 0, 0}},
      {2, {20, 28, 0, 0, 0}, {19, 27, 0, 0, 0}},
      {2, {21, 29, 0, 0, 0}, {20, 28, 0, 0, 0}},
      {2, {22, 30, 0, 0, 0}, {21, 29, 0, 0, 0}},
      {2, {23, 31, 0, 0, 0}, {22, 30, 0, 0, 0}},
  };
  // RB per level: root (phase-4-only) 16; nj<=2 levels 32; big levels 64
  static const int rbs[11] = {16, 64, 64, 64, 64, 64, 32, 32, 32, 32, 32};

  int pbase = 0;
  for (int L = 0; L < 11; ++L) {
    int bpj = ROWS / rbs[L];
    int blocks = levels[L].nj * bpj;
    if (rbs[L] == 64) {
      fused_level<64><<<blocks, 256, 0, stream>>>(
          z, emb, W1, b1, lng, lnb, W2, b2, nrm, zq, idxo, partials, levels[L], pbase);
    } else if (rbs[L] == 32) {
      fused_level<32><<<blocks, 256, 0, stream>>>(
          z, emb, W1, b1, lng, lnb, W2, b2, nrm, zq, idxo, partials, levels[L], pbase);
    } else {
      fused_level<16><<<blocks, 256, 0, stream>>>(
          z, emb, W1, b1, lng, lnb, W2, b2, nrm, zq, idxo, partials, levels[L], pbase);
    }
    pbase += blocks;
  }
  loss_reduce<<<1, 256, 0, stream>>>(partials, pbase, loss);
}

// Round 10
// 2042.699 us; speedup vs baseline: 1.1442x; 1.1442x over previous
//
#include <hip/hip_runtime.h>

#define NJ 32
#define NE 1024
#define CD 128
#define HID 256
#define ROWS 8192

struct Lv { int nj; int j[5]; int p[5]; };

// ---------------------------------------------------------------------------
// codebook norms: nrm[j*NE+n] = sum_c emb[j][n][c]^2   (4 lanes per code row)
// ---------------------------------------------------------------------------
__global__ __launch_bounds__(256) void norms_kernel(const float* __restrict__ emb,
                                                    float* __restrict__ nrm) {
  int gid = blockIdx.x * 256 + threadIdx.x;
  int n = gid >> 2, l = gid & 3;           // n in [0, NJ*NE)
  const float* row = emb + (size_t)n * CD;
  float s = 0.f;
#pragma unroll
  for (int i = 0; i < 8; ++i) {
    float4 v = *(const float4*)&row[(l + 4 * i) * 4];
    s += v.x * v.x + v.y * v.y + v.z * v.z + v.w * v.w;
  }
  s += __shfl_xor(s, 1);
  s += __shfl_xor(s, 2);
  if (l == 0) nrm[n] = s;
}

// ---------------------------------------------------------------------------
// fused per-level kernel. Single [128][HSP] LDS buffer aliased xs -> as_ -> hs
// plus es[16][260] staging; W1/W2/nrm read from global (L1/L2). LDS = 51.5 KB
// at RB=64 -> 3 blocks/CU.
// Phase 1: rg=tid>>5 rows, cg=tid&31 cols {qcA,qcB}; x staged in two 128-dim
//          chunks (zq-parent dims 0-127, z dims 128-255).
// Phase 3: rr=tid>>4 rows, cc=tid&15 cols {cc*4, 64+cc*4}.
// Phase 4: wave w4 owns R4 rows; lane l4 owns codes {l4*4..+3} per 256-chunk.
// ---------------------------------------------------------------------------
template <int RB>
__global__ __launch_bounds__(256) void fused_level(
    const float* __restrict__ z, const float* __restrict__ emb,
    const float* __restrict__ W1, const float* __restrict__ b1,
    const float* __restrict__ lng, const float* __restrict__ lnb,
    const float* __restrict__ W2, const float* __restrict__ b2,
    const float* __restrict__ nrm,
    float* __restrict__ zq, float* __restrict__ idx_out,
    float* __restrict__ partials, Lv lv, int pbase) {
  constexpr int RPG = RB / 8;          // rows/thread, phase 1
  constexpr int R3  = RB / 16;         // rows/thread, phase 3
  constexpr int R4  = RB / 4;          // rows/thread, phase 4
  constexpr int HSP = RB + 4;
  constexpr int BPJ = ROWS / RB;
  constexpr int HS  = 128 * HSP;
  constexpr int SMEM = HS + 16 * 260;

  __shared__ __align__(16) float smem[SMEM];
  __shared__ float wsum[4];
  float* xs  = smem;                   // phase 1 chunk: [128 dims][HSP]
  float* as_ = smem;                   // phase 3 input halves
  float* hs  = smem;                   // phase 3 out / phase 4
  float* es  = smem + HS;              // phase 4: [16][260]

  const int tid = threadIdx.x;
  const int rg = tid >> 5, cg = tid & 31;
  const int u = cg & 15;
  const int qcA = (cg >> 4) * 128 + u * 4;
  const int qcB = qcA + 64;
  const int jl = blockIdx.x / BPJ;
  const int row0 = (blockIdx.x % BPJ) * RB;
  const int jj = lv.j[jl], pj = lv.p[jl];
  const size_t rstride = (size_t)NJ * CD;

  if (pj >= 0) {
    // ====== phase 1: a1 = [e_parent | z_j] @ W1 (W1 global; xs chunked) ====
    float acc1[RPG][8];
#pragma unroll
    for (int r = 0; r < RPG; ++r)
#pragma unroll
      for (int c = 0; c < 8; ++c) acc1[r][c] = 0.f;

#pragma unroll 1
    for (int ch = 0; ch < 2; ++ch) {
      if (ch) __syncthreads();   // chunk-0 readers done before overwrite
      // stage 128-dim chunk (transposed): coalesced float4 loads
#pragma unroll
      for (int v = 0; v < RB / 8; ++v) {
        int idx = v * 256 + tid;
        int r = idx >> 5, q = idx & 31;
        const float* src = (ch == 0)
            ? (zq + (size_t)(row0 + r) * rstride + (size_t)pj * CD + q * 4)
            : (z  + (size_t)(row0 + r) * rstride + (size_t)jj * CD + q * 4);
        float4 x4 = *(const float4*)src;
        xs[(q * 4 + 0) * HSP + r] = x4.x;
        xs[(q * 4 + 1) * HSP + r] = x4.y;
        xs[(q * 4 + 2) * HSP + r] = x4.z;
        xs[(q * 4 + 3) * HSP + r] = x4.w;
      }
      __syncthreads();
#pragma unroll 4
      for (int kk = 0; kk < 128; ++kk) {
        float xr[RPG], wc[8];
        const float* Wrow = &W1[(size_t)(ch * 128 + kk) * HID];
        *(float4*)&wc[0] = *(const float4*)&Wrow[qcA];
        *(float4*)&wc[4] = *(const float4*)&Wrow[qcB];
        if constexpr (RPG >= 4) {
#pragma unroll
          for (int g = 0; g < RPG / 4; ++g)
            *(float4*)&xr[g * 4] = *(const float4*)&xs[kk * HSP + rg * RPG + g * 4];
        } else {
#pragma unroll
          for (int g = 0; g < RPG; ++g) xr[g] = xs[kk * HSP + rg * RPG + g];
        }
#pragma unroll
        for (int r = 0; r < RPG; ++r)
#pragma unroll
          for (int c = 0; c < 8; ++c)
            acc1[r][c] += xr[r] * wc[c];
      }
    }

    // ====== phase 2: +b1, LayerNorm, ReLU — round-1 bit-exact tree =========
    {
      float bb[8], gg[8], be[8];
      *(float4*)&bb[0] = *(const float4*)&b1[qcA];
      *(float4*)&bb[4] = *(const float4*)&b1[qcB];
      *(float4*)&gg[0] = *(const float4*)&lng[qcA];
      *(float4*)&gg[4] = *(const float4*)&lng[qcB];
      *(float4*)&be[0] = *(const float4*)&lnb[qcA];
      *(float4*)&be[4] = *(const float4*)&lnb[qcB];
#pragma unroll
      for (int r = 0; r < RPG; ++r) {
        float s0 = 0.f, q0 = 0.f;
#pragma unroll
        for (int j = 0; j < 8; ++j) {
          float v = acc1[r][j] + bb[j];
          acc1[r][j] = v;
          s0 += v; q0 += v * v;
        }
        float si = __shfl_xor(s0, 16), qi = __shfl_xor(q0, 16);
        float s1 = si, q1 = qi;
#pragma unroll
        for (int j = 0; j < 8; ++j) {
          float v = acc1[r][j];
          s1 += v; q1 += v * v;
        }
#pragma unroll
        for (int m = 1; m < 16; m <<= 1) {
          s1 += __shfl_xor(s1, m); q1 += __shfl_xor(q1, m);
        }
        float s2 = __shfl_xor(s1, 16), q2 = __shfl_xor(q1, 16);
        float Sx = (cg & 16) ? s1 : s2;
        float Qx = (cg & 16) ? q1 : q2;
        float mu = Sx * (1.f / HID);
        float va = Qx * (1.f / HID) - mu * mu;
        float iv = 1.f / sqrtf(va + 1e-5f);
#pragma unroll
        for (int j = 0; j < 8; ++j) {
          float a = (acc1[r][j] - mu) * iv * gg[j] + be[j];
          acc1[r][j] = fmaxf(a, 0.f);
        }
      }
    }

    // ====== phase 3: h = a @ W2 + b2 (W2 global; as_ halves aliased) ======
    const int cc = tid & 15, rr = tid >> 4;
    const int qA = cc * 4, qB = qA + 64;
    float acc2[R3][8];
#pragma unroll
    for (int r = 0; r < R3; ++r)
#pragma unroll
      for (int c = 0; c < 8; ++c) acc2[r][c] = 0.f;

#pragma unroll 1
    for (int half = 0; half < 2; ++half) {
      __syncthreads();   // xs readers (half 0) / as_ half-0 readers done
      if ((cg >> 4) == half) {
#pragma unroll
        for (int j = 0; j < 8; ++j) {
          int kl = (j >> 2) * 64 + u * 4 + (j & 3);
#pragma unroll
          for (int g = 0; g < RPG; ++g)
            as_[kl * HSP + rg * RPG + g] = acc1[g][j];
        }
      }
      __syncthreads();
#pragma unroll 4
      for (int kk = 0; kk < 128; ++kk) {
        float ar[R3], w2[8];
        const float* Wrow = &W2[(size_t)(half * 128 + kk) * CD];
        *(float4*)&w2[0] = *(const float4*)&Wrow[qA];
        *(float4*)&w2[4] = *(const float4*)&Wrow[qB];
        if constexpr (R3 >= 4) {
#pragma unroll
          for (int g = 0; g < R3 / 4; ++g)
            *(float4*)&ar[g * 4] = *(const float4*)&as_[kk * HSP + rr * R3 + g * 4];
        } else {
#pragma unroll
          for (int g = 0; g < R3; ++g) ar[g] = as_[kk * HSP + rr * R3 + g];
        }
#pragma unroll
        for (int r = 0; r < R3; ++r)
#pragma unroll
          for (int c = 0; c < 8; ++c)
            acc2[r][c] += ar[r] * w2[c];
      }
    }
    __syncthreads();   // all as_ reads done; buffer becomes hs
    {
      float bbA[4], bbB[4];
      *(float4*)&bbA[0] = *(const float4*)&b2[qA];
      *(float4*)&bbB[0] = *(const float4*)&b2[qB];
#pragma unroll
      for (int c = 0; c < 8; ++c) {
        int col = (c < 4) ? (qA + c) : (qB + c - 4);
        float bb2 = (c < 4) ? bbA[c] : bbB[c - 4];
#pragma unroll
        for (int r = 0; r < R3; ++r)
          hs[col * HSP + rr * R3 + r] = acc2[r][c] + bb2;
      }
    }
  } else {
    // root joint: h = z_j directly
#pragma unroll
    for (int v = 0; v < RB / 8; ++v) {
      int idx = v * 256 + tid;
      int r = idx >> 5, c4 = idx & 31;
      float4 vz = *(const float4*)&z[(size_t)(row0 + r) * rstride + (size_t)jj * CD + c4 * 4];
      hs[(c4 * 4 + 0) * HSP + r] = vz.x;
      hs[(c4 * 4 + 1) * HSP + r] = vz.y;
      hs[(c4 * 4 + 2) * HSP + r] = vz.z;
      hs[(c4 * 4 + 3) * HSP + r] = vz.w;
    }
  }

  // ====== phase 4: d = ||E||^2 - 2 h.E ; 4 chunks x 256 codes;
  //        R4 rows x 4 codes per thread; simple staged es[16][260] ==========
  const int w4 = tid >> 6;     // wave owns rows w4*R4 .. +R4-1
  const int l4 = tid & 63;     // lane owns codes {l4*4..+3} per chunk
  float mnv[R4]; int mni[R4];
#pragma unroll
  for (int r = 0; r < R4; ++r) { mnv[r] = 3.402823e38f; mni[r] = 0; }
  const float* embJ = emb + (size_t)jj * NE * CD;
  const float* nrmJ = nrm + jj * NE;

#pragma unroll 1
  for (int p = 0; p < 4; ++p) {
    float4 nr = *(const float4*)&nrmJ[p * 256 + l4 * 4];  // per-lane, global
    float acc4[R4][4];
#pragma unroll
    for (int r = 0; r < R4; ++r)
#pragma unroll
      for (int c = 0; c < 4; ++c) acc4[r][c] = 0.f;

#pragma unroll 1
    for (int kc = 0; kc < 8; ++kc) {
      __syncthreads();   // hs ready (first round) / es WAR (later rounds)
      // stage e chunk [16 dims][256 codes] (coalesced 64B per 4 lanes)
#pragma unroll
      for (int v = 0; v < 4; ++v) {
        int idx = v * 256 + tid;
        int n = idx >> 2, kq = idx & 3;
        float4 ev = *(const float4*)&embJ[(size_t)(p * 256 + n) * CD + kc * 16 + kq * 4];
        es[(kq * 4 + 0) * 260 + n] = ev.x;
        es[(kq * 4 + 1) * 260 + n] = ev.y;
        es[(kq * 4 + 2) * 260 + n] = ev.z;
        es[(kq * 4 + 3) * 260 + n] = ev.w;
      }
      __syncthreads();   // es ready
#pragma unroll 4
      for (int kk = 0; kk < 16; ++kk) {
        int c = kc * 16 + kk;
        float hr[R4], ec[4];
#pragma unroll
        for (int g = 0; g < R4 / 4; ++g)
          *(float4*)&hr[g * 4] = *(const float4*)&hs[c * HSP + w4 * R4 + g * 4];
        *(float4*)&ec[0] = *(const float4*)&es[kk * 260 + l4 * 4];
#pragma unroll
        for (int r = 0; r < R4; ++r)
#pragma unroll
          for (int c2 = 0; c2 < 4; ++c2)
            acc4[r][c2] += hr[r] * ec[c2];
      }
    }
    // min update, ascending-n order with strict < (first-occurrence ties)
    {
      float nrr[4] = {nr.x, nr.y, nr.z, nr.w};
#pragma unroll
      for (int r = 0; r < R4; ++r) {
#pragma unroll
        for (int j = 0; j < 4; ++j) {
          float d = nrr[j] - 2.f * acc4[r][j];
          int n = p * 256 + l4 * 4 + j;
          if (d < mnv[r]) { mnv[r] = d; mni[r] = n; }
        }
      }
    }
  }

  // cross-lane argmin reduce over 64 lanes, tie -> smaller index
#pragma unroll
  for (int r = 0; r < R4; ++r) {
    float mv = mnv[r]; int mi = mni[r];
#pragma unroll
    for (int m = 1; m < 64; m <<= 1) {
      float om = __shfl_xor(mv, m); int oi = __shfl_xor(mi, m);
      if (om < mv || (om == mv && oi < mi)) { mv = om; mi = oi; }
    }
    mnv[r] = mv; mni[r] = mi;
  }

  // gather e, write z_q + indices, accumulate loss (lane covers 2 cols)
  float lsum = 0.f;
#pragma unroll
  for (int r = 0; r < R4; ++r) {
    int row = w4 * R4 + r;
    int id = mni[r];
    const float* erow = embJ + (size_t)id * CD;
    float2 ev = *(const float2*)&erow[l4 * 2];
    float h0 = hs[(l4 * 2 + 0) * HSP + row];
    float h1 = hs[(l4 * 2 + 1) * HSP + row];
    float dx = ev.x - h0, dy = ev.y - h1;
    lsum += dx * dx + dy * dy;
    *(float2*)&zq[(size_t)(row0 + row) * rstride + (size_t)jj * CD + l4 * 2] = ev;
    if (l4 == r) idx_out[(size_t)(row0 + row) * NJ + jj] = (float)id;
  }
#pragma unroll
  for (int m = 1; m < 64; m <<= 1) lsum += __shfl_xor(lsum, m);
  if (l4 == 0) wsum[w4] = lsum;
  __syncthreads();
  if (tid == 0) partials[pbase + blockIdx.x] = wsum[0] + wsum[1] + wsum[2] + wsum[3];
}

// ---------------------------------------------------------------------------
// deterministic loss reduction
// ---------------------------------------------------------------------------
__global__ __launch_bounds__(256) void loss_reduce(const float* __restrict__ p, int n,
                                                   float* __restrict__ out) {
  __shared__ float ws[4];
  float s = 0.f;
  for (int i = threadIdx.x; i < n; i += 256) s += p[i];
#pragma unroll
  for (int m = 1; m < 64; m <<= 1) s += __shfl_xor(s, m);
  if ((threadIdx.x & 63) == 0) ws[threadIdx.x >> 6] = s;
  __syncthreads();
  if (threadIdx.x == 0)
    out[0] = (ws[0] + ws[1] + ws[2] + ws[3]) * (1.25f / (1048576.f * 32.f));
}

extern "C" void kernel_launch(void* const* d_in, const int* in_sizes, int n_in,
                              void* d_out, int out_size, void* d_ws, size_t ws_size,
                              hipStream_t stream) {
  const float* z = (const float*)d_in[0];
  const float* emb = (const float*)d_in[1];
  const float* W1 = (const float*)d_in[2];
  const float* b1 = (const float*)d_in[3];
  const float* lng = (const float*)d_in[4];
  const float* lnb = (const float*)d_in[5];
  const float* W2 = (const float*)d_in[6];
  const float* b2 = (const float*)d_in[7];

  float* zq = (float*)d_out;
  float* loss = zq + (size_t)ROWS * NJ * CD;  // 33,554,432
  float* idxo = loss + 1;

  float* nrm = (float*)d_ws;           // NJ*NE floats
  float* partials = nrm + NJ * NE;     // <= 5760 floats

  norms_kernel<<<NJ * NE * 4 / 256, 256, 0, stream>>>(emb, nrm);

  static const Lv levels[11] = {
      {1, {0, 0, 0, 0, 0}, {-1, 0, 0, 0, 0}},
      {3, {1, 6, 11, 0, 0}, {0, 0, 0, 0, 0}},
      {3, {2, 7, 12, 0, 0}, {1, 6, 11, 0, 0}},
      {5, {3, 8, 13, 16, 24}, {2, 7, 12, 12, 12}},
      {5, {4, 9, 14, 17, 25}, {3, 8, 13, 16, 24}},
      {5, {5, 10, 15, 18, 26}, {4, 9, 14, 17, 25}},
      {2, {19, 27, 0, 0, 0}, {18, 26, 0, 0, 0}},
      {2, {20, 28, 0, 0, 0}, {19, 27, 0, 0, 0}},
      {2, {21, 29, 0, 0, 0}, {20, 28, 0, 0, 0}},
      {2, {22, 30, 0, 0, 0}, {21, 29, 0, 0, 0}},
      {2, {23, 31, 0, 0, 0}, {22, 30, 0, 0, 0}},
  };
  // RB per level: root (phase-4-only) 16; nj<=2 levels 32; big levels 64
  static const int rbs[11] = {16, 64, 64, 64, 64, 64, 32, 32, 32, 32, 32};

  int pbase = 0;
  for (int L = 0; L < 11; ++L) {
    int bpj = ROWS / rbs[L];
    int blocks = levels[L].nj * bpj;
    if (rbs[L] == 64) {
      fused_level<64><<<blocks, 256, 0, stream>>>(
          z, emb, W1, b1, lng, lnb, W2, b2, nrm, zq, idxo, partials, levels[L], pbase);
    } else if (rbs[L] == 32) {
      fused_level<32><<<blocks, 256, 0, stream>>>(
          z, emb, W1, b1, lng, lnb, W2, b2, nrm, zq, idxo, partials, levels[L], pbase);
    } else {
      fused_level<16><<<blocks, 256, 0, stream>>>(
          z, emb, W1, b1, lng, lnb, W2, b2, nrm, zq, idxo, partials, levels[L], pbase);
    }
    pbase += blocks;
  }
  loss_reduce<<<1, 256, 0, stream>>>(partials, pbase, loss);
}

// Round 13
// 1879.157 us; speedup vs baseline: 1.2438x; 1.0870x over previous
//
#include <hip/hip_runtime.h>

#define NJ 32
#define NE 1024
#define CD 128
#define HID 256
#define ROWS 8192

struct Lv { int nj; int j[5]; int p[5]; };

// ---------------------------------------------------------------------------
// codebook norms: nrm[j*NE+n] = sum_c emb[j][n][c]^2   (4 lanes per code row)
// ---------------------------------------------------------------------------
__global__ __launch_bounds__(256) void norms_kernel(const float* __restrict__ emb,
                                                    float* __restrict__ nrm) {
  int gid = blockIdx.x * 256 + threadIdx.x;
  int n = gid >> 2, l = gid & 3;           // n in [0, NJ*NE)
  const float* row = emb + (size_t)n * CD;
  float s = 0.f;
#pragma unroll
  for (int i = 0; i < 8; ++i) {
    float4 v = *(const float4*)&row[(l + 4 * i) * 4];
    s += v.x * v.x + v.y * v.y + v.z * v.z + v.w * v.w;
  }
  s += __shfl_xor(s, 1);
  s += __shfl_xor(s, 2);
  if (l == 0) nrm[n] = s;
}

// ---------------------------------------------------------------------------
// fused per-level kernel. Phases 1-3 (MLP): rg = tid>>5 (8 groups of RPG
// rows), cg = tid&31 owning col quads {b*128+u*4, +64}. Phase 4 (VQ):
// wave w4 = tid>>6 owns R4 = RB/4 rows; 64 lanes own codes {l*4..+3} and
// {256+l*4..+3} of each 512-code chunk (row reads become wave-broadcasts,
// code reads 2 contiguous b128 -> LDS port demand ~4x lower than 8x16).
// LDS aliasing (floats):
//   phase1: xs[32][HSP] @0, ws1[32][264] @32*HSP
//   phase3: as_[128][HSP] @0, ws2[16][132] @128*HSP
//   ph3end: hs[128][HSP] @0 (as_ dead)
//   phase4: hs @0, es[16][516] @128*HSP, nsm[512] @128*HSP+8256
// ---------------------------------------------------------------------------
template <int RB>
__global__ __launch_bounds__(256) void fused_level(
    const float* __restrict__ z, const float* __restrict__ emb,
    const float* __restrict__ W1, const float* __restrict__ b1,
    const float* __restrict__ lng, const float* __restrict__ lnb,
    const float* __restrict__ W2, const float* __restrict__ b2,
    const float* __restrict__ nrm,
    float* __restrict__ zq, float* __restrict__ idx_out,
    float* __restrict__ partials, Lv lv, int pbase) {
  constexpr int RPG = RB / 8;          // rows/thread, phases 1-3
  constexpr int R4 = RB / 4;           // rows/thread, phase 4
  constexpr int HSP = RB + 4;
  constexpr int BPJ = ROWS / RB;
  constexpr int XS_SZ = 32 * HSP;
  constexpr int HS_SZ = 128 * HSP;
  constexpr int P1 = XS_SZ + 8448;
  constexpr int P3 = HS_SZ + 2112;
  constexpr int P4 = HS_SZ + 16 * 516 + 512;
  constexpr int SM12 = (P1 > P3) ? P1 : P3;
  constexpr int SMEM = (SM12 > P4) ? SM12 : P4;

  __shared__ __align__(16) float smem[SMEM];
  __shared__ float wsum[4];
  float* xs  = smem;
  float* ws1 = smem + XS_SZ;
  float* as_ = smem;
  float* ws2 = smem + HS_SZ;
  float* hs  = smem;
  float* es  = smem + HS_SZ;
  float* nsm = smem + HS_SZ + 16 * 516;

  const int tid = threadIdx.x;
  const int rg = tid >> 5, cg = tid & 31;
  const int u = cg & 15;
  const int qcA = (cg >> 4) * 128 + u * 4;
  const int qcB = qcA + 64;
  const int jl = blockIdx.x / BPJ;
  const int row0 = (blockIdx.x % BPJ) * RB;
  const int jj = lv.j[jl], pj = lv.p[jl];
  const size_t rstride = (size_t)NJ * CD;

  if (pj >= 0) {
    // ================= phase 1: a1 = [e_parent | z_j] @ W1 =================
    float acc1[RPG][8];
#pragma unroll
    for (int r = 0; r < RPG; ++r)
#pragma unroll
      for (int c = 0; c < 8; ++c) acc1[r][c] = 0.f;

#pragma unroll 1
    for (int ks = 0; ks < 8; ++ks) {
#pragma unroll
      for (int uu = 0; uu < RB / 32; ++uu) {
        int idx = uu * 256 + tid;
        int r = idx >> 3, kq = idx & 7;
        const float* src = (ks < 4)
            ? (zq + (size_t)(row0 + r) * rstride + (size_t)pj * CD + (ks * 32 + kq * 4))
            : (z  + (size_t)(row0 + r) * rstride + (size_t)jj * CD + (ks * 32 - 128 + kq * 4));
        float4 v = *(const float4*)src;
        xs[(kq * 4 + 0) * HSP + r] = v.x;
        xs[(kq * 4 + 1) * HSP + r] = v.y;
        xs[(kq * 4 + 2) * HSP + r] = v.z;
        xs[(kq * 4 + 3) * HSP + r] = v.w;
      }
#pragma unroll
      for (int v8 = 0; v8 < 8; ++v8) {
        int idx = v8 * 256 + tid;
        int k = idx >> 6, c4 = idx & 63;
        *(float4*)&ws1[k * 264 + c4 * 4] =
            *(const float4*)&W1[(size_t)(ks * 32 + k) * HID + c4 * 4];
      }
      __syncthreads();
#pragma unroll 2
      for (int kk = 0; kk < 32; ++kk) {
        float xr[RPG], wc[8];
#pragma unroll
        for (int g = 0; g < RPG / 4; ++g)
          *(float4*)&xr[g * 4] = *(const float4*)&xs[kk * HSP + rg * RPG + g * 4];
        *(float4*)&wc[0] = *(const float4*)&ws1[kk * 264 + qcA];
        *(float4*)&wc[4] = *(const float4*)&ws1[kk * 264 + qcB];
#pragma unroll
        for (int r = 0; r < RPG; ++r)
#pragma unroll
          for (int c = 0; c < 8; ++c)
            acc1[r][c] += xr[r] * wc[c];
      }
      __syncthreads();
    }

    // ====== phase 2: +b1, LayerNorm, ReLU — round-1 bit-exact tree =========
    {
      float bb[8], gg[8], be[8];
      *(float4*)&bb[0] = *(const float4*)&b1[qcA];
      *(float4*)&bb[4] = *(const float4*)&b1[qcB];
      *(float4*)&gg[0] = *(const float4*)&lng[qcA];
      *(float4*)&gg[4] = *(const float4*)&lng[qcB];
      *(float4*)&be[0] = *(const float4*)&lnb[qcA];
      *(float4*)&be[4] = *(const float4*)&lnb[qcB];
#pragma unroll
      for (int r = 0; r < RPG; ++r) {
        float s0 = 0.f, q0 = 0.f;
#pragma unroll
        for (int j = 0; j < 8; ++j) {
          float v = acc1[r][j] + bb[j];
          acc1[r][j] = v;
          s0 += v; q0 += v * v;
        }
        float si = __shfl_xor(s0, 16), qi = __shfl_xor(q0, 16);
        float s1 = si, q1 = qi;
#pragma unroll
        for (int j = 0; j < 8; ++j) {
          float v = acc1[r][j];
          s1 += v; q1 += v * v;
        }
#pragma unroll
        for (int m = 1; m < 16; m <<= 1) {
          s1 += __shfl_xor(s1, m); q1 += __shfl_xor(q1, m);
        }
        float s2 = __shfl_xor(s1, 16), q2 = __shfl_xor(q1, 16);
        float Sx = (cg & 16) ? s1 : s2;
        float Qx = (cg & 16) ? q1 : q2;
        float mu = Sx * (1.f / HID);
        float va = Qx * (1.f / HID) - mu * mu;
        float iv = 1.f / sqrtf(va + 1e-5f);
#pragma unroll
        for (int j = 0; j < 8; ++j) {
          float a = (acc1[r][j] - mu) * iv * gg[j] + be[j];
          acc1[r][j] = fmaxf(a, 0.f);
        }
      }
    }

    // ================= phase 3: h = a @ W2 + b2 (two 128-k halves) =========
    float acc2[RPG][4];
#pragma unroll
    for (int r = 0; r < RPG; ++r)
#pragma unroll
      for (int c = 0; c < 4; ++c) acc2[r][c] = 0.f;

#pragma unroll 1
    for (int half = 0; half < 2; ++half) {
      __syncthreads();
      if ((cg >> 4) == half) {
#pragma unroll
        for (int j = 0; j < 8; ++j) {
          int kl = (j >> 2) * 64 + u * 4 + (j & 3);
#pragma unroll
          for (int g = 0; g < RPG; ++g)
            as_[kl * HSP + rg * RPG + g] = acc1[g][j];
        }
      }
      __syncthreads();
#pragma unroll 1
      for (int kc = 0; kc < 8; ++kc) {
#pragma unroll
        for (int v = 0; v < 2; ++v) {
          int idx = v * 256 + tid;
          int k = idx >> 5, c4 = idx & 31;
          *(float4*)&ws2[k * 132 + c4 * 4] =
              *(const float4*)&W2[(size_t)(half * 128 + kc * 16 + k) * CD + c4 * 4];
        }
        __syncthreads();
#pragma unroll 2
        for (int kk = 0; kk < 16; ++kk) {
          float ar[RPG], wc2[4];
#pragma unroll
          for (int g = 0; g < RPG / 4; ++g)
            *(float4*)&ar[g * 4] =
                *(const float4*)&as_[(kc * 16 + kk) * HSP + rg * RPG + g * 4];
          *(float4*)&wc2[0] = *(const float4*)&ws2[kk * 132 + cg * 4];
#pragma unroll
          for (int r = 0; r < RPG; ++r)
#pragma unroll
            for (int c = 0; c < 4; ++c)
              acc2[r][c] += ar[r] * wc2[c];
        }
        __syncthreads();
      }
    }
    {
      float4 bv = *(const float4*)&b2[cg * 4];
      float bb2[4] = {bv.x, bv.y, bv.z, bv.w};
#pragma unroll
      for (int c = 0; c < 4; ++c) {
#pragma unroll
        for (int g = 0; g < RPG / 4; ++g)
          *(float4*)&hs[(cg * 4 + c) * HSP + rg * RPG + g * 4] =
              make_float4(acc2[g * 4 + 0][c] + bb2[c], acc2[g * 4 + 1][c] + bb2[c],
                          acc2[g * 4 + 2][c] + bb2[c], acc2[g * 4 + 3][c] + bb2[c]);
      }
    }
  } else {
    // root joint: h = z_j directly
#pragma unroll
    for (int v = 0; v < RB / 8; ++v) {
      int idx = v * 256 + tid;
      int r = idx >> 5, c4 = idx & 31;
      float4 vz = *(const float4*)&z[(size_t)(row0 + r) * rstride + (size_t)jj * CD + c4 * 4];
      hs[(c4 * 4 + 0) * HSP + r] = vz.x;
      hs[(c4 * 4 + 1) * HSP + r] = vz.y;
      hs[(c4 * 4 + 2) * HSP + r] = vz.z;
      hs[(c4 * 4 + 3) * HSP + r] = vz.w;
    }
  }

  // ====== phase 4: d = ||E||^2 - 2 h.E ; R4 rows x 8 codes per thread ======
  const int w4 = tid >> 6;     // wave owns rows w4*R4 .. +R4-1
  const int l4 = tid & 63;     // lane owns codes {l4*4..+3} and {256+l4*4..+3}
  float mnv[R4]; int mni[R4];
#pragma unroll
  for (int r = 0; r < R4; ++r) { mnv[r] = 3.402823e38f; mni[r] = 0; }
  const float* embJ = emb + (size_t)jj * NE * CD;
  const float* nrmJ = nrm + jj * NE;

#pragma unroll 1
  for (int p = 0; p < 2; ++p) {
    __syncthreads();  // hs ready (p=0); es/nsm WAR from previous chunk
    if (tid < 128) {
      *(float4*)&nsm[tid * 4] = *(const float4*)&nrmJ[p * 512 + tid * 4];
    }
    float acc4[R4][8];
#pragma unroll
    for (int r = 0; r < R4; ++r)
#pragma unroll
      for (int c = 0; c < 8; ++c) acc4[r][c] = 0.f;

#pragma unroll 1
    for (int kc = 0; kc < 8; ++kc) {
      // stage e chunk [16 dims][512 codes]
#pragma unroll
      for (int v = 0; v < 8; ++v) {
        int idx = v * 256 + tid;
        int n = idx >> 2, kq = idx & 3;
        float4 ev = *(const float4*)&embJ[(size_t)(p * 512 + n) * CD + kc * 16 + kq * 4];
        es[(kq * 4 + 0) * 516 + n] = ev.x;
        es[(kq * 4 + 1) * 516 + n] = ev.y;
        es[(kq * 4 + 2) * 516 + n] = ev.z;
        es[(kq * 4 + 3) * 516 + n] = ev.w;
      }
      __syncthreads();
#pragma unroll 2
      for (int kk = 0; kk < 16; ++kk) {
        int c = kc * 16 + kk;
        float hr[R4], ec[8];
#pragma unroll
        for (int g = 0; g < R4 / 4; ++g)
          *(float4*)&hr[g * 4] = *(const float4*)&hs[c * HSP + w4 * R4 + g * 4];
        *(float4*)&ec[0] = *(const float4*)&es[kk * 516 + l4 * 4];
        *(float4*)&ec[4] = *(const float4*)&es[kk * 516 + 256 + l4 * 4];
#pragma unroll
        for (int r = 0; r < R4; ++r)
#pragma unroll
          for (int c2 = 0; c2 < 8; ++c2)
            acc4[r][c2] += hr[r] * ec[c2];
      }
      __syncthreads();
    }
    // min update, ascending-n order with strict < (first-occurrence ties)
#pragma unroll
    for (int r = 0; r < R4; ++r) {
#pragma unroll
      for (int q = 0; q < 2; ++q) {
#pragma unroll
        for (int j = 0; j < 4; ++j) {
          int nl = q * 256 + l4 * 4 + j;
          float d = nsm[nl] - 2.f * acc4[r][q * 4 + j];
          int n = p * 512 + nl;
          if (d < mnv[r]) { mnv[r] = d; mni[r] = n; }
        }
      }
    }
  }

  // cross-lane argmin reduce over 64 lanes, tie -> smaller index
#pragma unroll
  for (int r = 0; r < R4; ++r) {
    float mv = mnv[r]; int mi = mni[r];
#pragma unroll
    for (int m = 1; m < 64; m <<= 1) {
      float om = __shfl_xor(mv, m); int oi = __shfl_xor(mi, m);
      if (om < mv || (om == mv && oi < mi)) { mv = om; mi = oi; }
    }
    mnv[r] = mv; mni[r] = mi;
  }

  // gather e, write z_q + indices, accumulate loss (lane covers 2 cols)
  float lsum = 0.f;
#pragma unroll
  for (int r = 0; r < R4; ++r) {
    int row = w4 * R4 + r;
    int id = mni[r];
    const float* erow = embJ + (size_t)id * CD;
    float2 ev = *(const float2*)&erow[l4 * 2];
    float h0 = hs[(l4 * 2 + 0) * HSP + row];
    float h1 = hs[(l4 * 2 + 1) * HSP + row];
    float dx = ev.x - h0, dy = ev.y - h1;
    lsum += dx * dx + dy * dy;
    *(float2*)&zq[(size_t)(row0 + row) * rstride + (size_t)jj * CD + l4 * 2] = ev;
    if (l4 == r) idx_out[(size_t)(row0 + row) * NJ + jj] = (float)id;
  }
#pragma unroll
  for (int m = 1; m < 64; m <<= 1) lsum += __shfl_xor(lsum, m);
  if (l4 == 0) wsum[w4] = lsum;
  __syncthreads();
  if (tid == 0) partials[pbase + blockIdx.x] = wsum[0] + wsum[1] + wsum[2] + wsum[3];
}

// ---------------------------------------------------------------------------
// deterministic loss reduction
// ---------------------------------------------------------------------------
__global__ __launch_bounds__(256) void loss_reduce(const float* __restrict__ p, int n,
                                                   float* __restrict__ out) {
  __shared__ float ws[4];
  float s = 0.f;
  for (int i = threadIdx.x; i < n; i += 256) s += p[i];
#pragma unroll
  for (int m = 1; m < 64; m <<= 1) s += __shfl_xor(s, m);
  if ((threadIdx.x & 63) == 0) ws[threadIdx.x >> 6] = s;
  __syncthreads();
  if (threadIdx.x == 0)
    out[0] = (ws[0] + ws[1] + ws[2] + ws[3]) * (1.25f / (1048576.f * 32.f));
}

extern "C" void kernel_launch(void* const* d_in, const int* in_sizes, int n_in,
                              void* d_out, int out_size, void* d_ws, size_t ws_size,
                              hipStream_t stream) {
  const float* z = (const float*)d_in[0];
  const float* emb = (const float*)d_in[1];
  const float* W1 = (const float*)d_in[2];
  const float* b1 = (const float*)d_in[3];
  const float* lng = (const float*)d_in[4];
  const float* lnb = (const float*)d_in[5];
  const float* W2 = (const float*)d_in[6];
  const float* b2 = (const float*)d_in[7];

  float* zq = (float*)d_out;
  float* loss = zq + (size_t)ROWS * NJ * CD;  // 33,554,432
  float* idxo = loss + 1;

  float* nrm = (float*)d_ws;           // NJ*NE floats
  float* partials = nrm + NJ * NE;     // <= 5760 floats

  norms_kernel<<<NJ * NE * 4 / 256, 256, 0, stream>>>(emb, nrm);

  static const Lv levels[11] = {
      {1, {0, 0, 0, 0, 0}, {-1, 0, 0, 0, 0}},
      {3, {1, 6, 11, 0, 0}, {0, 0, 0, 0, 0}},
      {3, {2, 7, 12, 0, 0}, {1, 6, 11, 0, 0}},
      {5, {3, 8, 13, 16, 24}, {2, 7, 12, 12, 12}},
      {5, {4, 9, 14, 17, 25}, {3, 8, 13, 16, 24}},
      {5, {5, 10, 15, 18, 26}, {4, 9, 14, 17, 25}},
      {2, {19, 27, 0, 0, 0}, {18, 26, 0, 0, 0}},
      {2, {20, 28, 0, 0, 0}, {19, 27, 0, 0, 0}},
      {2, {21, 29, 0, 0, 0}, {20, 28, 0, 0, 0}},
      {2, {22, 30, 0, 0, 0}, {21, 29, 0, 0, 0}},
      {2, {23, 31, 0, 0, 0}, {22, 30, 0, 0, 0}},
  };
  // RB per level: root (phase-4-only) 16; nj<=2 levels 32; big levels 64
  static const int rbs[11] = {16, 64, 64, 64, 64, 64, 32, 32, 32, 32, 32};

  int pbase = 0;
  for (int L = 0; L < 11; ++L) {
    int bpj = ROWS / rbs[L];
    int blocks = levels[L].nj * bpj;
    if (rbs[L] == 64) {
      fused_level<64><<<blocks, 256, 0, stream>>>(
          z, emb, W1, b1, lng, lnb, W2, b2, nrm, zq, idxo, partials, levels[L], pbase);
    } else if (rbs[L] == 32) {
      fused_level<32><<<blocks, 256, 0, stream>>>(
          z, emb, W1, b1, lng, lnb, W2, b2, nrm, zq, idxo, partials, levels[L], pbase);
    } else {
      fused_level<16><<<blocks, 256, 0, stream>>>(
          z, emb, W1, b1, lng, lnb, W2, b2, nrm, zq, idxo, partials, levels[L], pbase);
    }
    pbase += blocks;
  }
  loss_reduce<<<1, 256, 0, stream>>>(partials, pbase, loss);
}

// Round 14
// 1834.006 us; speedup vs baseline: 1.2744x; 1.0246x over previous
//
#include <hip/hip_runtime.h>

#define NJ 32
#define NE 1024
#define CD 128
#define HID 256
#define ROWS 8192

struct Lv { int nj; int j[5]; int p[5]; };

typedef __attribute__((ext_vector_type(2))) float f2;

// packed fp32 FMA: acc.{lo,hi} += s0.lo * s1.{lo,hi}   (broadcast lo of s0)
#define PKLO(acc, s0, s1) \
  asm("v_pk_fma_f32 %0, %1, %2, %0 op_sel:[0,0,0] op_sel_hi:[0,1,1]" \
      : "+v"(acc) : "v"(s0), "v"(s1))
// packed fp32 FMA: acc.{lo,hi} += s0.hi * s1.{lo,hi}   (broadcast hi of s0)
#define PKHI(acc, s0, s1) \
  asm("v_pk_fma_f32 %0, %1, %2, %0 op_sel:[1,0,0] op_sel_hi:[1,1,1]" \
      : "+v"(acc) : "v"(s0), "v"(s1))

// ---------------------------------------------------------------------------
// codebook norms: nrm[j*NE+n] = sum_c emb[j][n][c]^2   (4 lanes per code row)
// ---------------------------------------------------------------------------
__global__ __launch_bounds__(256) void norms_kernel(const float* __restrict__ emb,
                                                    float* __restrict__ nrm) {
  int gid = blockIdx.x * 256 + threadIdx.x;
  int n = gid >> 2, l = gid & 3;           // n in [0, NJ*NE)
  const float* row = emb + (size_t)n * CD;
  float s = 0.f;
#pragma unroll
  for (int i = 0; i < 8; ++i) {
    float4 v = *(const float4*)&row[(l + 4 * i) * 4];
    s += v.x * v.x + v.y * v.y + v.z * v.z + v.w * v.w;
  }
  s += __shfl_xor(s, 1);
  s += __shfl_xor(s, 2);
  if (l == 0) nrm[n] = s;
}

// ---------------------------------------------------------------------------
// fused per-level kernel — round-13 structure with v_pk_fma_f32 inner loops.
// Phases 1-3 (MLP): rg = tid>>5 rows, cg = tid&31 col quads {qcA,qcB}.
// Phase 4 (VQ): wave w4 owns R4 rows; lane l4 owns codes {l4*4, 256+l4*4}
// per 512-code chunk. All per-accumulator FP chains identical to round 13
// (pk halves compute the same IEEE fma per element) -> bit-identical output.
// ---------------------------------------------------------------------------
template <int RB>
__global__ __launch_bounds__(256) void fused_level(
    const float* __restrict__ z, const float* __restrict__ emb,
    const float* __restrict__ W1, const float* __restrict__ b1,
    const float* __restrict__ lng, const float* __restrict__ lnb,
    const float* __restrict__ W2, const float* __restrict__ b2,
    const float* __restrict__ nrm,
    float* __restrict__ zq, float* __restrict__ idx_out,
    float* __restrict__ partials, Lv lv, int pbase) {
  constexpr int RPG = RB / 8;          // rows/thread, phases 1-3
  constexpr int R4 = RB / 4;           // rows/thread, phase 4
  constexpr int HSP = RB + 4;
  constexpr int BPJ = ROWS / RB;
  constexpr int XS_SZ = 32 * HSP;
  constexpr int HS_SZ = 128 * HSP;
  constexpr int P1 = XS_SZ + 8448;
  constexpr int P3 = HS_SZ + 2112;
  constexpr int P4 = HS_SZ + 16 * 516 + 512;
  constexpr int SM12 = (P1 > P3) ? P1 : P3;
  constexpr int SMEM = (SM12 > P4) ? SM12 : P4;

  __shared__ __align__(16) float smem[SMEM];
  __shared__ float wsum[4];
  float* xs  = smem;
  float* ws1 = smem + XS_SZ;
  float* as_ = smem;
  float* ws2 = smem + HS_SZ;
  float* hs  = smem;
  float* es  = smem + HS_SZ;
  float* nsm = smem + HS_SZ + 16 * 516;

  const int tid = threadIdx.x;
  const int rg = tid >> 5, cg = tid & 31;
  const int u = cg & 15;
  const int qcA = (cg >> 4) * 128 + u * 4;
  const int qcB = qcA + 64;
  const int jl = blockIdx.x / BPJ;
  const int row0 = (blockIdx.x % BPJ) * RB;
  const int jj = lv.j[jl], pj = lv.p[jl];
  const size_t rstride = (size_t)NJ * CD;

  if (pj >= 0) {
    // ================= phase 1: a1 = [e_parent | z_j] @ W1 =================
    f2 acc1[RPG][4];
#pragma unroll
    for (int r = 0; r < RPG; ++r)
#pragma unroll
      for (int c = 0; c < 4; ++c) acc1[r][c] = (f2){0.f, 0.f};

#pragma unroll 1
    for (int ks = 0; ks < 8; ++ks) {
#pragma unroll
      for (int uu = 0; uu < RB / 32; ++uu) {
        int idx = uu * 256 + tid;
        int r = idx >> 3, kq = idx & 7;
        const float* src = (ks < 4)
            ? (zq + (size_t)(row0 + r) * rstride + (size_t)pj * CD + (ks * 32 + kq * 4))
            : (z  + (size_t)(row0 + r) * rstride + (size_t)jj * CD + (ks * 32 - 128 + kq * 4));
        float4 v = *(const float4*)src;
        xs[(kq * 4 + 0) * HSP + r] = v.x;
        xs[(kq * 4 + 1) * HSP + r] = v.y;
        xs[(kq * 4 + 2) * HSP + r] = v.z;
        xs[(kq * 4 + 3) * HSP + r] = v.w;
      }
#pragma unroll
      for (int v8 = 0; v8 < 8; ++v8) {
        int idx = v8 * 256 + tid;
        int k = idx >> 6, c4 = idx & 63;
        *(float4*)&ws1[k * 264 + c4 * 4] =
            *(const float4*)&W1[(size_t)(ks * 32 + k) * HID + c4 * 4];
      }
      __syncthreads();
#pragma unroll 2
      for (int kk = 0; kk < 32; ++kk) {
        f2 xrp[RPG / 2], wcp[4];
#pragma unroll
        for (int g = 0; g < RPG / 4; ++g)
          *(float4*)&xrp[g * 2] = *(const float4*)&xs[kk * HSP + rg * RPG + g * 4];
        *(float4*)&wcp[0] = *(const float4*)&ws1[kk * 264 + qcA];
        *(float4*)&wcp[2] = *(const float4*)&ws1[kk * 264 + qcB];
#pragma unroll
        for (int r2 = 0; r2 < RPG / 2; ++r2) {
#pragma unroll
          for (int c = 0; c < 4; ++c) PKLO(acc1[2 * r2][c], xrp[r2], wcp[c]);
#pragma unroll
          for (int c = 0; c < 4; ++c) PKHI(acc1[2 * r2 + 1][c], xrp[r2], wcp[c]);
        }
      }
      __syncthreads();
    }

    // ====== phase 2: +b1, LayerNorm, ReLU — round-1 bit-exact tree =========
    {
      float bb[8], gg[8], be[8];
      *(float4*)&bb[0] = *(const float4*)&b1[qcA];
      *(float4*)&bb[4] = *(const float4*)&b1[qcB];
      *(float4*)&gg[0] = *(const float4*)&lng[qcA];
      *(float4*)&gg[4] = *(const float4*)&lng[qcB];
      *(float4*)&be[0] = *(const float4*)&lnb[qcA];
      *(float4*)&be[4] = *(const float4*)&lnb[qcB];
#pragma unroll
      for (int r = 0; r < RPG; ++r) {
        float s0 = 0.f, q0 = 0.f;
#pragma unroll
        for (int j = 0; j < 8; ++j) {
          float v = acc1[r][j >> 1][j & 1] + bb[j];
          acc1[r][j >> 1][j & 1] = v;
          s0 += v; q0 += v * v;
        }
        float si = __shfl_xor(s0, 16), qi = __shfl_xor(q0, 16);
        float s1 = si, q1 = qi;
#pragma unroll
        for (int j = 0; j < 8; ++j) {
          float v = acc1[r][j >> 1][j & 1];
          s1 += v; q1 += v * v;
        }
#pragma unroll
        for (int m = 1; m < 16; m <<= 1) {
          s1 += __shfl_xor(s1, m); q1 += __shfl_xor(q1, m);
        }
        float s2 = __shfl_xor(s1, 16), q2 = __shfl_xor(q1, 16);
        float Sx = (cg & 16) ? s1 : s2;
        float Qx = (cg & 16) ? q1 : q2;
        float mu = Sx * (1.f / HID);
        float va = Qx * (1.f / HID) - mu * mu;
        float iv = 1.f / sqrtf(va + 1e-5f);
#pragma unroll
        for (int j = 0; j < 8; ++j) {
          float a = (acc1[r][j >> 1][j & 1] - mu) * iv * gg[j] + be[j];
          acc1[r][j >> 1][j & 1] = fmaxf(a, 0.f);
        }
      }
    }

    // ================= phase 3: h = a @ W2 + b2 (two 128-k halves) =========
    f2 acc2[RPG][2];
#pragma unroll
    for (int r = 0; r < RPG; ++r)
#pragma unroll
      for (int c = 0; c < 2; ++c) acc2[r][c] = (f2){0.f, 0.f};

#pragma unroll 1
    for (int half = 0; half < 2; ++half) {
      __syncthreads();
      if ((cg >> 4) == half) {
#pragma unroll
        for (int j = 0; j < 8; ++j) {
          int kl = (j >> 2) * 64 + u * 4 + (j & 3);
#pragma unroll
          for (int g = 0; g < RPG; ++g)
            as_[kl * HSP + rg * RPG + g] = acc1[g][j >> 1][j & 1];
        }
      }
      __syncthreads();
#pragma unroll 1
      for (int kc = 0; kc < 8; ++kc) {
#pragma unroll
        for (int v = 0; v < 2; ++v) {
          int idx = v * 256 + tid;
          int k = idx >> 5, c4 = idx & 31;
          *(float4*)&ws2[k * 132 + c4 * 4] =
              *(const float4*)&W2[(size_t)(half * 128 + kc * 16 + k) * CD + c4 * 4];
        }
        __syncthreads();
#pragma unroll 2
        for (int kk = 0; kk < 16; ++kk) {
          f2 arp[RPG / 2], w2p[2];
#pragma unroll
          for (int g = 0; g < RPG / 4; ++g)
            *(float4*)&arp[g * 2] =
                *(const float4*)&as_[(kc * 16 + kk) * HSP + rg * RPG + g * 4];
          *(float4*)&w2p[0] = *(const float4*)&ws2[kk * 132 + cg * 4];
#pragma unroll
          for (int r2 = 0; r2 < RPG / 2; ++r2) {
#pragma unroll
            for (int c = 0; c < 2; ++c) PKLO(acc2[2 * r2][c], arp[r2], w2p[c]);
#pragma unroll
            for (int c = 0; c < 2; ++c) PKHI(acc2[2 * r2 + 1][c], arp[r2], w2p[c]);
          }
        }
        __syncthreads();
      }
    }
    {
      float4 bv = *(const float4*)&b2[cg * 4];
      float bb2[4] = {bv.x, bv.y, bv.z, bv.w};
#pragma unroll
      for (int c = 0; c < 4; ++c) {
#pragma unroll
        for (int g = 0; g < RPG / 4; ++g)
          *(float4*)&hs[(cg * 4 + c) * HSP + rg * RPG + g * 4] =
              make_float4(acc2[g * 4 + 0][c >> 1][c & 1] + bb2[c],
                          acc2[g * 4 + 1][c >> 1][c & 1] + bb2[c],
                          acc2[g * 4 + 2][c >> 1][c & 1] + bb2[c],
                          acc2[g * 4 + 3][c >> 1][c & 1] + bb2[c]);
      }
    }
  } else {
    // root joint: h = z_j directly
#pragma unroll
    for (int v = 0; v < RB / 8; ++v) {
      int idx = v * 256 + tid;
      int r = idx >> 5, c4 = idx & 31;
      float4 vz = *(const float4*)&z[(size_t)(row0 + r) * rstride + (size_t)jj * CD + c4 * 4];
      hs[(c4 * 4 + 0) * HSP + r] = vz.x;
      hs[(c4 * 4 + 1) * HSP + r] = vz.y;
      hs[(c4 * 4 + 2) * HSP + r] = vz.z;
      hs[(c4 * 4 + 3) * HSP + r] = vz.w;
    }
  }

  // ====== phase 4: d = ||E||^2 - 2 h.E ; R4 rows x 8 codes per thread ======
  const int w4 = tid >> 6;     // wave owns rows w4*R4 .. +R4-1
  const int l4 = tid & 63;     // lane owns codes {l4*4..+3} and {256+l4*4..+3}
  float mnv[R4]; int mni[R4];
#pragma unroll
  for (int r = 0; r < R4; ++r) { mnv[r] = 3.402823e38f; mni[r] = 0; }
  const float* embJ = emb + (size_t)jj * NE * CD;
  const float* nrmJ = nrm + jj * NE;

#pragma unroll 1
  for (int p = 0; p < 2; ++p) {
    __syncthreads();  // hs ready (p=0); es/nsm WAR from previous chunk
    if (tid < 128) {
      *(float4*)&nsm[tid * 4] = *(const float4*)&nrmJ[p * 512 + tid * 4];
    }
    f2 acc4[R4][4];
#pragma unroll
    for (int r = 0; r < R4; ++r)
#pragma unroll
      for (int c = 0; c < 4; ++c) acc4[r][c] = (f2){0.f, 0.f};

#pragma unroll 1
    for (int kc = 0; kc < 8; ++kc) {
      // stage e chunk [16 dims][512 codes]
#pragma unroll
      for (int v = 0; v < 8; ++v) {
        int idx = v * 256 + tid;
        int n = idx >> 2, kq = idx & 3;
        float4 ev = *(const float4*)&embJ[(size_t)(p * 512 + n) * CD + kc * 16 + kq * 4];
        es[(kq * 4 + 0) * 516 + n] = ev.x;
        es[(kq * 4 + 1) * 516 + n] = ev.y;
        es[(kq * 4 + 2) * 516 + n] = ev.z;
        es[(kq * 4 + 3) * 516 + n] = ev.w;
      }
      __syncthreads();
#pragma unroll 2
      for (int kk = 0; kk < 16; ++kk) {
        int c = kc * 16 + kk;
        f2 hrp[R4 / 2], ecp[4];
#pragma unroll
        for (int g = 0; g < R4 / 4; ++g)
          *(float4*)&hrp[g * 2] = *(const float4*)&hs[c * HSP + w4 * R4 + g * 4];
        *(float4*)&ecp[0] = *(const float4*)&es[kk * 516 + l4 * 4];
        *(float4*)&ecp[2] = *(const float4*)&es[kk * 516 + 256 + l4 * 4];
#pragma unroll
        for (int r2 = 0; r2 < R4 / 2; ++r2) {
#pragma unroll
          for (int c2 = 0; c2 < 4; ++c2) PKLO(acc4[2 * r2][c2], hrp[r2], ecp[c2]);
#pragma unroll
          for (int c2 = 0; c2 < 4; ++c2) PKHI(acc4[2 * r2 + 1][c2], hrp[r2], ecp[c2]);
        }
      }
      __syncthreads();
    }
    // min update, ascending-n order with strict < (first-occurrence ties)
#pragma unroll
    for (int r = 0; r < R4; ++r) {
#pragma unroll
      for (int q = 0; q < 2; ++q) {
#pragma unroll
        for (int j = 0; j < 4; ++j) {
          int nl = q * 256 + l4 * 4 + j;
          int ci = q * 4 + j;
          float d = nsm[nl] - 2.f * acc4[r][ci >> 1][ci & 1];
          int n = p * 512 + nl;
          if (d < mnv[r]) { mnv[r] = d; mni[r] = n; }
        }
      }
    }
  }

  // cross-lane argmin reduce over 64 lanes, tie -> smaller index
#pragma unroll
  for (int r = 0; r < R4; ++r) {
    float mv = mnv[r]; int mi = mni[r];
#pragma unroll
    for (int m = 1; m < 64; m <<= 1) {
      float om = __shfl_xor(mv, m); int oi = __shfl_xor(mi, m);
      if (om < mv || (om == mv && oi < mi)) { mv = om; mi = oi; }
    }
    mnv[r] = mv; mni[r] = mi;
  }

  // gather e, write z_q + indices, accumulate loss (lane covers 2 cols)
  float lsum = 0.f;
#pragma unroll
  for (int r = 0; r < R4; ++r) {
    int row = w4 * R4 + r;
    int id = mni[r];
    const float* erow = embJ + (size_t)id * CD;
    float2 ev = *(const float2*)&erow[l4 * 2];
    float h0 = hs[(l4 * 2 + 0) * HSP + row];
    float h1 = hs[(l4 * 2 + 1) * HSP + row];
    float dx = ev.x - h0, dy = ev.y - h1;
    lsum += dx * dx + dy * dy;
    *(float2*)&zq[(size_t)(row0 + row) * rstride + (size_t)jj * CD + l4 * 2] = ev;
    if (l4 == r) idx_out[(size_t)(row0 + row) * NJ + jj] = (float)id;
  }
#pragma unroll
  for (int m = 1; m < 64; m <<= 1) lsum += __shfl_xor(lsum, m);
  if (l4 == 0) wsum[w4] = lsum;
  __syncthreads();
  if (tid == 0) partials[pbase + blockIdx.x] = wsum[0] + wsum[1] + wsum[2] + wsum[3];
}

// ---------------------------------------------------------------------------
// deterministic loss reduction
// ---------------------------------------------------------------------------
__global__ __launch_bounds__(256) void loss_reduce(const float* __restrict__ p, int n,
                                                   float* __restrict__ out) {
  __shared__ float ws[4];
  float s = 0.f;
  for (int i = threadIdx.x; i < n; i += 256) s += p[i];
#pragma unroll
  for (int m = 1; m < 64; m <<= 1) s += __shfl_xor(s, m);
  if ((threadIdx.x & 63) == 0) ws[threadIdx.x >> 6] = s;
  __syncthreads();
  if (threadIdx.x == 0)
    out[0] = (ws[0] + ws[1] + ws[2] + ws[3]) * (1.25f / (1048576.f * 32.f));
}

extern "C" void kernel_launch(void* const* d_in, const int* in_sizes, int n_in,
                              void* d_out, int out_size, void* d_ws, size_t ws_size,
                              hipStream_t stream) {
  const float* z = (const float*)d_in[0];
  const float* emb = (const float*)d_in[1];
  const float* W1 = (const float*)d_in[2];
  const float* b1 = (const float*)d_in[3];
  const float* lng = (const float*)d_in[4];
  const float* lnb = (const float*)d_in[5];
  const float* W2 = (const float*)d_in[6];
  const float* b2 = (const float*)d_in[7];

  float* zq = (float*)d_out;
  float* loss = zq + (size_t)ROWS * NJ * CD;  // 33,554,432
  float* idxo = loss + 1;

  float* nrm = (float*)d_ws;           // NJ*NE floats
  float* partials = nrm + NJ * NE;     // <= 5760 floats

  norms_kernel<<<NJ * NE * 4 / 256, 256, 0, stream>>>(emb, nrm);

  static const Lv levels[11] = {
      {1, {0, 0, 0, 0, 0}, {-1, 0, 0, 0, 0}},
      {3, {1, 6, 11, 0, 0}, {0, 0, 0, 0, 0}},
      {3, {2, 7, 12, 0, 0}, {1, 6, 11, 0, 0}},
      {5, {3, 8, 13, 16, 24}, {2, 7, 12, 12, 12}},
      {5, {4, 9, 14, 17, 25}, {3, 8, 13, 16, 24}},
      {5, {5, 10, 15, 18, 26}, {4, 9, 14, 17, 25}},
      {2, {19, 27, 0, 0, 0}, {18, 26, 0, 0, 0}},
      {2, {20, 28, 0, 0, 0}, {19, 27, 0, 0, 0}},
      {2, {21, 29, 0, 0, 0}, {20, 28, 0, 0, 0}},
      {2, {22, 30, 0, 0, 0}, {21, 29, 0, 0, 0}},
      {2, {23, 31, 0, 0, 0}, {22, 30, 0, 0, 0}},
  };
  // RB per level: root (phase-4-only) 16; nj<=2 levels 32; big levels 64
  static const int rbs[11] = {16, 64, 64, 64, 64, 64, 32, 32, 32, 32, 32};

  int pbase = 0;
  for (int L = 0; L < 11; ++L) {
    int bpj = ROWS / rbs[L];
    int blocks = levels[L].nj * bpj;
    if (rbs[L] == 64) {
      fused_level<64><<<blocks, 256, 0, stream>>>(
          z, emb, W1, b1, lng, lnb, W2, b2, nrm, zq, idxo, partials, levels[L], pbase);
    } else if (rbs[L] == 32) {
      fused_level<32><<<blocks, 256, 0, stream>>>(
          z, emb, W1, b1, lng, lnb, W2, b2, nrm, zq, idxo, partials, levels[L], pbase);
    } else {
      fused_level<16><<<blocks, 256, 0, stream>>>(
          z, emb, W1, b1, lng, lnb, W2, b2, nrm, zq, idxo, partials, levels[L], pbase);
    }
    pbase += blocks;
  }
  loss_reduce<<<1, 256, 0, stream>>>(partials, pbase, loss);
}